// Round 1
// baseline (462.863 us; speedup 1.0000x reference)
//
#include <hip/hip_runtime.h>

#define B 256
#define S 197
#define D 768
#define P 20
#define L 5
#define T 10
#define K 5

// Output element offsets (float32, concatenated in return order)
#define ROWS_PE 272                     // (T+K)*L + S = 75 + 197
#define SZ_PE   (B * ROWS_PE * D)       // 53,477,376
#define OFF_RS  ((long)SZ_PE)           // reduce_sim scalar
#define OFF_TOK (OFF_RS + 1)            // tokens [B,75,D]
#define SZ_TOK  (B * (T + K) * L * D)   // 14,745,600
#define OFF_IDX (OFF_TOK + SZ_TOK)      // idx_pruned [B,K] as float
#define OFF_XN  (OFF_IDX + B * K)       // x_norm [B,D]

// Kernel 1: stream x_embed once — copy into prompted_embedding rows [75,272)
// and accumulate per-(b,tile) partial column sums for the mean.
// grid (4 tiles, B), block 192; thread t owns float4 columns 4t..4t+3.
__global__ void k_mean_copy(const float* __restrict__ x, float* __restrict__ pe,
                            float* __restrict__ partial) {
    const int tile = blockIdx.x;
    const int b = blockIdx.y;
    const int t = threadIdx.x;              // 0..191
    const int s0 = tile * 50;
    const int s1 = (s0 + 50 < S) ? s0 + 50 : S;
    const float4* x4 = (const float4*)x;
    float4* o4 = (float4*)pe;
    const int xbase = (b * S) * (D / 4) + t;             // float4 units
    const int obase = (b * ROWS_PE + (T + K) * L) * (D / 4) + t;
    float4 acc = make_float4(0.f, 0.f, 0.f, 0.f);
    for (int s = s0; s < s1; ++s) {
        float4 v = x4[xbase + s * (D / 4)];
        acc.x += v.x; acc.y += v.y; acc.z += v.z; acc.w += v.w;
        o4[obase + s * (D / 4)] = v;
    }
    ((float4*)partial)[(b * 4 + tile) * (D / 4) + t] = acc;
}

// Kernel 2: blocks [0,B) -> x_norm from partial sums; blocks [B,B+P) -> p_norm.
// block 256; thread t owns columns t, t+256, t+512.
__global__ void k_norm(const float* __restrict__ partial, const float* __restrict__ pkey,
                       float* __restrict__ xnorm_out, float* __restrict__ pnorm) {
    const int blk = blockIdx.x;
    const int t = threadIdx.x;
    float v0, v1, v2;
    if (blk < B) {
        v0 = v1 = v2 = 0.f;
        for (int tile = 0; tile < 4; ++tile) {
            const float* p = partial + (blk * 4 + tile) * D;
            v0 += p[t]; v1 += p[t + 256]; v2 += p[t + 512];
        }
        const float invS = 1.0f / (float)S;
        v0 *= invS; v1 *= invS; v2 *= invS;
    } else {
        const float* p = pkey + (blk - B) * D;
        v0 = p[t]; v1 = p[t + 256]; v2 = p[t + 512];
    }
    float ss = v0 * v0 + v1 * v1 + v2 * v2;
    for (int o = 32; o > 0; o >>= 1) ss += __shfl_down(ss, o);
    __shared__ float red[4];
    const int lane = t & 63, wid = t >> 6;
    if (lane == 0) red[wid] = ss;
    __syncthreads();
    if (t == 0) {
        float s = red[0] + red[1] + red[2] + red[3];
        red[0] = rsqrtf(fmaxf(s, 1e-12f));
    }
    __syncthreads();
    const float r = red[0];
    float* dst = (blk < B) ? (xnorm_out + blk * D) : (pnorm + (blk - B) * D);
    dst[t] = v0 * r; dst[t + 256] = v1 * r; dst[t + 512] = v2 * r;
}

// Kernel 3: per-b similarity (P dots of length D), serial top-K with jax
// tie-break (strict >, ascending index scan), threshold, key counting.
__global__ void k_simtopk(const float* __restrict__ xnorm, const float* __restrict__ pnorm,
                          float* __restrict__ idxp_f, int* __restrict__ idx_ws,
                          int* __restrict__ keycnt) {
    const int b = blockIdx.x;
    const int t = threadIdx.x;              // 256
    __shared__ float xs[D];
    __shared__ float sim[P];
    xs[t] = xnorm[b * D + t];
    xs[t + 256] = xnorm[b * D + t + 256];
    xs[t + 512] = xnorm[b * D + t + 512];
    __syncthreads();
    const int wid = t >> 6, lane = t & 63;
    for (int p = wid; p < P; p += 4) {
        float acc = 0.f;
        const float* pr = pnorm + p * D;
        for (int d = lane; d < D; d += 64) acc += xs[d] * pr[d];
        for (int o = 32; o > 0; o >>= 1) acc += __shfl_down(acc, o);
        if (lane == 0) sim[p] = acc;
    }
    __syncthreads();
    if (t == 0) {
        bool used[P];
        for (int p = 0; p < P; ++p) used[p] = false;
        for (int k = 0; k < K; ++k) {
            float best = -INFINITY; int bi = 0;
            for (int p = 0; p < P; ++p)
                if (!used[p] && sim[p] > best) { best = sim[p]; bi = p; }
            used[bi] = true;
            const int oi = (best > 0.0f) ? bi : -1;
            idxp_f[b * K + k] = (float)oi;
            idx_ws[b * K + k] = oi;
            if (oi >= 0) atomicAdd(&keycnt[bi], 1);
        }
    }
}

// Kernel 4: build token rows; write both tokens output and prompted_embedding
// rows [0,75). Scalar dword stores (tokens region is only 4B-aligned).
// grid (75, B), block 256; thread t owns columns t, t+256, t+512.
__global__ void k_tokens(const float* __restrict__ prompt, const float* __restrict__ assist,
                         const int* __restrict__ idx_ws, float* __restrict__ pe,
                         float* __restrict__ tok) {
    const int j = blockIdx.x;               // 0..74
    const int b = blockIdx.y;
    const int t = threadIdx.x;
    float v0, v1, v2;
    if (j < T * L) {
        const float* src = assist + j * D;
        v0 = src[t]; v1 = src[t + 256]; v2 = src[t + 512];
    } else {
        const int k = (j - T * L) / L, l = (j - T * L) % L;
        const int idx = idx_ws[b * K + k];
        if (idx < 0) {
            v0 = v1 = v2 = 0.f;
        } else {
            const float* src = prompt + (idx * L + l) * D;
            v0 = src[t]; v1 = src[t + 256]; v2 = src[t + 512];
        }
    }
    float* d1 = pe + (long)(b * ROWS_PE + j) * D;
    d1[t] = v0; d1[t + 256] = v1; d1[t + 512] = v2;
    float* d2 = tok + (long)(b * (T + K) * L + j) * D;
    d2[t] = v0; d2[t + 256] = v1; d2[t + 512] = v2;
}

// Kernel 5: reduce_sim = (sum_b x_norm) . (sum_p cnt[p]*p_norm[p]) / B
__global__ void k_reduce(const float* __restrict__ xnorm, const float* __restrict__ pnorm,
                         const int* __restrict__ keycnt, float* __restrict__ rs) {
    const int t = threadIdx.x;              // 256
    __shared__ float cnt[P];
    if (t < P) cnt[t] = (float)keycnt[t];
    __syncthreads();
    float acc = 0.f;
    for (int c = 0; c < 3; ++c) {
        const int d = t + c * 256;
        float xsum = 0.f;
        for (int b = 0; b < B; ++b) xsum += xnorm[b * D + d];
        float kt = 0.f;
        for (int p = 0; p < P; ++p) kt += cnt[p] * pnorm[p * D + d];
        acc += xsum * kt;
    }
    for (int o = 32; o > 0; o >>= 1) acc += __shfl_down(acc, o);
    __shared__ float red[4];
    const int lane = t & 63, wid = t >> 6;
    if (lane == 0) red[wid] = acc;
    __syncthreads();
    if (t == 0) rs[0] = (red[0] + red[1] + red[2] + red[3]) * (1.0f / (float)B);
}

extern "C" void kernel_launch(void* const* d_in, const int* in_sizes, int n_in,
                              void* d_out, int out_size, void* d_ws, size_t ws_size,
                              hipStream_t stream) {
    const float* x      = (const float*)d_in[0];   // [B,S,D]
    const float* prompt = (const float*)d_in[1];   // [P,L,D]
    const float* pkey   = (const float*)d_in[2];   // [P,D]
    const float* assist = (const float*)d_in[3];   // [T,L,D]
    float* out = (float*)d_out;
    float* ws = (float*)d_ws;

    float* partial = ws;                            // B*4*D = 786,432 floats
    float* pnorm   = ws + B * 4 * D;                // P*D = 15,360 floats
    int*   idx_ws  = (int*)(pnorm + P * D);         // B*K ints
    int*   keycnt  = idx_ws + B * K;                // P ints

    hipMemsetAsync(keycnt, 0, P * sizeof(int), stream);

    k_mean_copy<<<dim3(4, B), 192, 0, stream>>>(x, out, partial);
    k_norm<<<B + P, 256, 0, stream>>>(partial, pkey, out + OFF_XN, pnorm);
    k_simtopk<<<B, 256, 0, stream>>>(out + OFF_XN, pnorm, out + OFF_IDX, idx_ws, keycnt);
    k_tokens<<<dim3((T + K) * L, B), 256, 0, stream>>>(prompt, assist, idx_ws, out, out + OFF_TOK);
    k_reduce<<<1, 256, 0, stream>>>(out + OFF_XN, pnorm, keycnt, out + OFF_RS);
}

// Round 2
// 462.398 us; speedup vs baseline: 1.0010x; 1.0010x over previous
//
#include <hip/hip_runtime.h>

#define B 256
#define S 197
#define D 768
#define P 20
#define L 5
#define T 10
#define K 5

// Output element offsets (float32, concatenated in return order)
#define ROWS_PE 272                     // (T+K)*L + S = 75 + 197
#define SZ_PE   (B * ROWS_PE * D)       // 53,477,376
#define OFF_RS  ((long)SZ_PE)           // reduce_sim scalar
#define OFF_TOK (OFF_RS + 1)            // tokens [B,75,D] — 4B-aligned only!
#define SZ_TOK  (B * (T + K) * L * D)   // 14,745,600
#define OFF_IDX (OFF_TOK + SZ_TOK)      // idx_pruned [B,K] as float
#define OFF_XN  (OFF_IDX + B * K)       // x_norm [B,D]

// Kernel 1: stream x_embed once — copy into prompted_embedding rows [75,272)
// and accumulate per-(b,tile) partial column sums for the mean.
// grid (4 tiles, B), block 192; thread t owns float4 columns 4t..4t+3.
__global__ void k_mean_copy(const float* __restrict__ x, float* __restrict__ pe,
                            float* __restrict__ partial) {
    const int tile = blockIdx.x;
    const int b = blockIdx.y;
    const int t = threadIdx.x;              // 0..191
    const int s0 = tile * 50;
    const int s1 = (s0 + 50 < S) ? s0 + 50 : S;
    const float4* x4 = (const float4*)x;
    float4* o4 = (float4*)pe;
    const int xbase = (b * S) * (D / 4) + t;             // float4 units
    const int obase = (b * ROWS_PE + (T + K) * L) * (D / 4) + t;
    float4 acc = make_float4(0.f, 0.f, 0.f, 0.f);
    for (int s = s0; s < s1; ++s) {
        float4 v = x4[xbase + s * (D / 4)];
        acc.x += v.x; acc.y += v.y; acc.z += v.z; acc.w += v.w;
        o4[obase + s * (D / 4)] = v;
    }
    ((float4*)partial)[(b * 4 + tile) * (D / 4) + t] = acc;
}

// Kernel 2 (fused norm+sim+topk): one block per b.
//  - reduce partial -> x_mean -> x_norm (write to out, atomicAdd into xsum)
//  - sim_p = (x_norm . pkey_p) * rsqrt(max(|pkey_p|^2, eps))  [p_norm never stored]
//  - serial top-K (jax tie semantics: strict >, ascending scan), threshold,
//    per-prompt selection counts via atomics.
__global__ void k_simtopk(const float* __restrict__ partial, const float* __restrict__ pkey,
                          float* __restrict__ xnorm_out, float* __restrict__ xsum,
                          float* __restrict__ idxp_f, int* __restrict__ idx_ws,
                          int* __restrict__ keycnt) {
    const int b = blockIdx.x;
    const int t = threadIdx.x;              // 256
    const int lane = t & 63, wid = t >> 6;
    __shared__ float xs[D];
    __shared__ float sim[P];
    __shared__ float red[4];

    // x_mean for columns t, t+256, t+512
    float v0 = 0.f, v1 = 0.f, v2 = 0.f;
    for (int tile = 0; tile < 4; ++tile) {
        const float* p = partial + (b * 4 + tile) * D;
        v0 += p[t]; v1 += p[t + 256]; v2 += p[t + 512];
    }
    const float invS = 1.0f / (float)S;
    v0 *= invS; v1 *= invS; v2 *= invS;
    float ss = v0 * v0 + v1 * v1 + v2 * v2;
    for (int o = 32; o > 0; o >>= 1) ss += __shfl_down(ss, o);
    if (lane == 0) red[wid] = ss;
    __syncthreads();
    if (t == 0) red[0] = rsqrtf(fmaxf(red[0] + red[1] + red[2] + red[3], 1e-12f));
    __syncthreads();
    const float r = red[0];
    v0 *= r; v1 *= r; v2 *= r;
    xs[t] = v0; xs[t + 256] = v1; xs[t + 512] = v2;
    xnorm_out[b * D + t] = v0;
    xnorm_out[b * D + t + 256] = v1;
    xnorm_out[b * D + t + 512] = v2;
    atomicAdd(&xsum[t], v0);
    atomicAdd(&xsum[t + 256], v1);
    atomicAdd(&xsum[t + 512], v2);
    __syncthreads();

    // similarities: wave `wid` handles prompts wid, wid+4, ...
    for (int p = wid; p < P; p += 4) {
        const float* pr = pkey + p * D;
        float axk = 0.f, akk = 0.f;
        for (int d = lane; d < D; d += 64) {
            const float kv = pr[d];
            axk += xs[d] * kv;
            akk += kv * kv;
        }
        for (int o = 32; o > 0; o >>= 1) {
            axk += __shfl_down(axk, o);
            akk += __shfl_down(akk, o);
        }
        if (lane == 0) sim[p] = axk * rsqrtf(fmaxf(akk, 1e-12f));
    }
    __syncthreads();
    if (t == 0) {
        bool used[P];
        for (int p = 0; p < P; ++p) used[p] = false;
        for (int k = 0; k < K; ++k) {
            float best = -INFINITY; int bi = 0;
            for (int p = 0; p < P; ++p)
                if (!used[p] && sim[p] > best) { best = sim[p]; bi = p; }
            used[bi] = true;
            const int oi = (best > 0.0f) ? bi : -1;
            idxp_f[b * K + k] = (float)oi;
            idx_ws[b * K + k] = oi;
            if (oi >= 0) atomicAdd(&keycnt[bi], 1);
        }
    }
}

// Kernel 3: build token rows; write both tokens output and prompted_embedding
// rows [0,75). pe gets float4 stores; tok is only 4B-aligned -> scalar dwords.
// grid (75, B), block 192; thread t owns columns 4t..4t+3.
__global__ void k_tokens(const float* __restrict__ prompt, const float* __restrict__ assist,
                         const int* __restrict__ idx_ws, float* __restrict__ pe,
                         float* __restrict__ tok) {
    const int j = blockIdx.x;               // 0..74
    const int b = blockIdx.y;
    const int t = threadIdx.x;              // 0..191
    float4 v;
    if (j < T * L) {
        v = ((const float4*)(assist + j * D))[t];
    } else {
        const int k = (j - T * L) / L, l = (j - T * L) % L;
        const int idx = idx_ws[b * K + k];
        if (idx < 0) v = make_float4(0.f, 0.f, 0.f, 0.f);
        else         v = ((const float4*)(prompt + (idx * L + l) * D))[t];
    }
    ((float4*)(pe + (long)(b * ROWS_PE + j) * D))[t] = v;
    float* d2 = tok + (long)(b * (T + K) * L + j) * D + 4 * t;
    d2[0] = v.x; d2[1] = v.y; d2[2] = v.z; d2[3] = v.w;
}

// Kernel 4: reduce_sim = xsum . (sum_p cnt_p * rsqrt(|pkey_p|^2) * pkey_p) / B
__global__ void k_reduce(const float* __restrict__ xsum, const float* __restrict__ pkey,
                         const int* __restrict__ keycnt, float* __restrict__ rs) {
    const int t = threadIdx.x;              // 256
    const int lane = t & 63, wid = t >> 6;
    __shared__ float coef[P];
    __shared__ float red[4];
    // coef[p] = cnt_p * rsqrt(|pkey_p|^2); wave wid handles p = wid, wid+4, ...
    for (int p = wid; p < P; p += 4) {
        const float* pr = pkey + p * D;
        float akk = 0.f;
        for (int d = lane; d < D; d += 64) { const float kv = pr[d]; akk += kv * kv; }
        for (int o = 32; o > 0; o >>= 1) akk += __shfl_down(akk, o);
        if (lane == 0) coef[p] = (float)keycnt[p] * rsqrtf(fmaxf(akk, 1e-12f));
    }
    __syncthreads();
    float acc = 0.f;
    for (int c = 0; c < 3; ++c) {
        const int d = t + c * 256;
        float kt = 0.f;
        for (int p = 0; p < P; ++p) kt += coef[p] * pkey[p * D + d];
        acc += xsum[d] * kt;
    }
    for (int o = 32; o > 0; o >>= 1) acc += __shfl_down(acc, o);
    if (lane == 0) red[wid] = acc;
    __syncthreads();
    if (t == 0) rs[0] = (red[0] + red[1] + red[2] + red[3]) * (1.0f / (float)B);
}

extern "C" void kernel_launch(void* const* d_in, const int* in_sizes, int n_in,
                              void* d_out, int out_size, void* d_ws, size_t ws_size,
                              hipStream_t stream) {
    const float* x      = (const float*)d_in[0];   // [B,S,D]
    const float* prompt = (const float*)d_in[1];   // [P,L,D]
    const float* pkey   = (const float*)d_in[2];   // [P,D]
    const float* assist = (const float*)d_in[3];   // [T,L,D]
    float* out = (float*)d_out;
    float* ws = (float*)d_ws;

    float* partial = ws;                            // B*4*D floats
    int*   keycnt  = (int*)(partial + B * 4 * D);   // P ints     (zeroed)
    float* xsum    = (float*)(keycnt + P);          // D floats   (zeroed)
    int*   idx_ws  = (int*)(xsum + D);              // B*K ints

    hipMemsetAsync(keycnt, 0, (P + D) * sizeof(float), stream);

    k_mean_copy<<<dim3(4, B), 192, 0, stream>>>(x, out, partial);
    k_simtopk<<<B, 256, 0, stream>>>(partial, pkey, out + OFF_XN, xsum,
                                     out + OFF_IDX, idx_ws, keycnt);
    k_tokens<<<dim3((T + K) * L, B), 192, 0, stream>>>(prompt, assist, idx_ws, out, out + OFF_TOK);
    k_reduce<<<1, 256, 0, stream>>>(xsum, pkey, keycnt, out + OFF_RS);
}